// Round 9
// baseline (1046.803 us; speedup 1.0000x reference)
//
#include <hip/hip_runtime.h>
#include <cstdint>

#define W 2048
#define H 512
#define K 32                     // halo depth = sync period (steps)
#define NW 8                     // waves per block
#define NSLOT 1058               // slots 0..1057 ; slot s <-> col s + cbase
// Split-array LDS layout per buffer (16B/slot both -> uniform full-exec b128 reads):
//   arrA: NSLOT x 4 dw: {c01,c23,c45,c67}   arrB: NSLOT x 4 dw: {c89, x-pair, 0, 0}
#define ABASE 0
#define BBASE (NSLOT*4)
#define BUFD  10248              // raw 8464, padded: 2 buffers = 82 KB -> 1 block/CU
#define FLOFF (2*BUFD)

typedef __fp16 h2    __attribute__((ext_vector_type(2)));
typedef __fp16 f16x8 __attribute__((ext_vector_type(8)));
typedef float  f32x16 __attribute__((ext_vector_type(16)));

static __device__ __forceinline__ h2 as_h2(uint32_t u){ union{uint32_t u; h2 h;} x; x.u=u; return x.h; }
static __device__ __forceinline__ uint32_t as_u32(h2 h){ union{uint32_t u; h2 h;} x; x.h=h; return x.u; }

__global__ __launch_bounds__(512, 1) void recurrent_kernel(
    const float* __restrict__ x,
    const float* __restrict__ w1, const float* __restrict__ b1,
    const float* __restrict__ w2, const float* __restrict__ b2,
    const float* __restrict__ wl, const float* __restrict__ bl,
    const float* __restrict__ wo, const float* __restrict__ bo,
    float* __restrict__ out, uint32_t* __restrict__ ws)
{
    extern __shared__ uint32_t lds[];
    const int tid  = threadIdx.x;
    const int b    = blockIdx.x & 7;     // batch
    const int hfl  = blockIdx.x >> 3;    // half: 0 = owns cols 0..1023, 1 = owns 1024..2047
    const int lane = tid & 63;
    const int wvL  = tid >> 6;           // wave 0..7
    const int m    = lane & 31;
    const int hh   = lane >> 5;

    const int cbase = hfl ? 991 : -1;    // col = slot + cbase
    const int EW    = hfl ? 0 : 7;       // edge wave (owns the halo tile)
    const bool isEW = (wvL == EW);
    const int nti   = isEW ? 5 : 4;      // tiles this wave computes
    const int hti   = hfl ? 0 : 4;       // local index of halo tile (edge wave)
    const int sti   = hfl ? 1 : 3;       // local index of boundary tile we SEND
    const int obase = (isEW && hfl) ? 1 : 0;  // first owned local tile for out-store

    for (int i = tid; i < 2*BUFD + NW; i += 512) lds[i] = 0;

    // ---- A fragments: weights resident in VGPRs ----
    f16x8 afrag[3];
    #pragma unroll
    for (int tap = 0; tap < 3; ++tap)
        #pragma unroll
        for (int j = 0; j < 8; ++j) {
            int k = 8*hh + j;
            float v = (m < 10 && k < 12) ? wl[(m*12 + k)*3 + tap] : 0.f;
            afrag[tap][j] = (__fp16)v;
        }
    h2 wop0, wop1, wop2;
    if (hh == 0) {
        wop0 = __builtin_amdgcn_cvt_pkrtz(wo[0], wo[1]);
        wop1 = __builtin_amdgcn_cvt_pkrtz(wo[2], wo[3]);
        wop2 = __builtin_amdgcn_cvt_pkrtz(wo[8], wo[9]);
    } else {
        wop0 = __builtin_amdgcn_cvt_pkrtz(wo[4], wo[5]);
        wop1 = __builtin_amdgcn_cvt_pkrtz(wo[6], wo[7]);
        wop2 = __builtin_amdgcn_cvt_pkrtz(0.f, 0.f);
    }
    f32x16 bias16;
    #pragma unroll
    for (int r = 0; r < 16; ++r) {
        int ch = (r & 3) + 8*(r >> 2) + 4*hh;
        bias16[r] = (r < 8 && ch < 10) ? bl[ch] : 0.f;
    }
    const float bov = bo[0];
    const int bpaddr = (lane ^ 32) << 2;
    const h2 hz = {(__fp16)0.f, (__fp16)0.f};

    const float* x1b = x + (((size_t)b*3 + 1)*H)*W;
    const float* x2b = x + (((size_t)b*3 + 2)*H)*W;
    float* outb = out + (size_t)b*H*W;

    // ---- per-wave tile geometry ----
    int rdi_[5], aw_[5], bw_[5], col_[5];
    bool wok[5], gated_[5];
    #pragma unroll
    for (int ti = 0; ti < 5; ++ti) {
        int gt = (hfl == 0) ? (ti == 4 ? 32 : 4*wvL + ti)
                            : (wvL == 0 ? ti : 4*wvL + 1 + ti);
        int sb = 32*gt + m;                    // read slot base (tap 0)
        rdi_[ti] = (hh ? BBASE : ABASE) + 4*sb;
        aw_[ti]  = ABASE + 4*(sb + 1) + 2*hh;
        bw_[ti]  = BBASE + 4*(sb + 1);
        col_[ti] = 32*gt + m + (hfl ? 992 : 0);
        wok[ti]  = (col_[ti] != 0) && (col_[ti] != W-1);
        // does this tile read another WAVE's slots? (cross-block halo is gate-free)
        if (!isEW)          gated_[ti] = (ti == 0) || (ti == 3);
        else if (hfl == 0)  gated_[ti] = (ti == 0);   // tile 3 reads own halo col
        else                gated_[ti] = (ti == 4);   // tile 0(halo),1..3 all own
    }
    uint32_t* fl = lds + FLOFF;
    const int na = (wvL == 0)    ? wvL : wvL - 1;
    const int nb = (wvL == NW-1) ? wvL : wvL + 1;

    // exchange records: [b][dir] : 512 dw each; parity slot 256 dw: tag@0, data@32+32*f+m
    uint32_t* rec_m = ws + (b*2 + hfl)*512;
    uint32_t* rec_o = ws + (b*2 + (1 - hfl))*512;

    // x-prefetch: wave-owned slots == this wave's ROW-WRITE slot range (contiguous).
    const int xbase = (hfl == 0) ? (128*wvL + 1) : (wvL == 0 ? 1 : 128*wvL + 33);
    const int xsl1 = xbase + lane;
    const int xsl2 = xbase + 64 + lane;
    const bool xe3 = isEW && (hh == 0);
    const int xsl3 = xbase + 128 + m;

    __syncthreads();   // zeros visible

    // ---- init: row0 for ALL slots (ghosts/guards included) + out[0] for owned ----
    for (int idx = tid; idx < NSLOT; idx += 512) {
        const int p = idx + cbase;                 // global col of slot idx
        float fi[3][5];
        #pragma unroll
        for (int l = 0; l < 5; ++l) {
            int v = p - 2 + l;
            bool ok = (v >= 0) && (v < W);
            fi[0][l] = ok ? x[(((size_t)b*3 + 0)*H + (H-1))*W + v] : 0.f;
            fi[1][l] = ok ? x1b[v] : 0.f;
            fi[2][l] = ok ? x2b[v] : 0.f;
        }
        float h1v[5][3];
        #pragma unroll
        for (int c = 0; c < 5; ++c)
            #pragma unroll
            for (int i3 = 0; i3 < 3; ++i3) {
                int u = p - 2 + i3;
                float a = b1[c];
                #pragma unroll
                for (int j = 0; j < 3; ++j)
                    #pragma unroll
                    for (int k = 0; k < 3; ++k)
                        a += w1[(c*3 + j)*3 + k] * fi[j][i3 + k];
                h1v[c][i3] = (u >= 0 && u <= W-3) ? fmaxf(a, 0.f) : 0.f;
            }
        const bool valid = (p >= 1) && (p <= W-2);
        float h2c[10];
        #pragma unroll
        for (int c2 = 0; c2 < 10; ++c2) {
            float a = b2[c2];
            #pragma unroll
            for (int c = 0; c < 5; ++c)
                #pragma unroll
                for (int k = 0; k < 3; ++k)
                    a += w2[(c2*5 + c)*3 + k] * h1v[c][k];
            h2c[c2] = valid ? fmaxf(a, 0.f) : 0.f;
        }
        uint4 wr;
        wr.x = as_u32(__builtin_amdgcn_cvt_pkrtz(h2c[0], h2c[1]));
        wr.y = as_u32(__builtin_amdgcn_cvt_pkrtz(h2c[2], h2c[3]));
        wr.z = as_u32(__builtin_amdgcn_cvt_pkrtz(h2c[4], h2c[5]));
        wr.w = as_u32(__builtin_amdgcn_cvt_pkrtz(h2c[6], h2c[7]));
        *(uint4*)(lds + ABASE + 4*idx) = wr;
        lds[BBASE + 4*idx] = as_u32(__builtin_amdgcn_cvt_pkrtz(h2c[8], h2c[9]));
        bool okp = (p >= 0) && (p < W);
        lds[BBASE + 4*idx + 1] = okp
            ? as_u32(__builtin_amdgcn_cvt_pkrtz(x1b[W + p], x2b[W + p])) : 0u;
        if (p >= hfl*1024 && p < hfl*1024 + 1024) {   // owned col -> out[0]
            float s = bov;
            #pragma unroll
            for (int c = 0; c < 10; ++c) s += wo[c]*h2c[c];
            outb[p] = s;
        }
    }
    __syncthreads();   // last block-wide barrier

    // ---- recurrence: interior-first wave pipeline + K-deep halo exchange ----
    #pragma unroll 1
    for (int t = 1; t < H; ++t) {
        const uint32_t* rb = lds + ((t - 1) & 1)*BUFD;   // row t-1 + x[t]
        uint32_t*       wb = lds + (t & 1)*BUFD;         // row t   + x[t+1]
        const bool sync = ((t & (K-1)) == 0);            // t = 32,64,...,480

        // x[t+1] prefetch (wave-owned slots)
        float xa1, xa2, xb1, xb2, xc1 = 0.f, xc2 = 0.f;
        const bool pf = (t + 1 < H);
        if (pf) {
            const float* r1 = x1b + (size_t)(t + 1)*W + cbase;
            const float* r2 = x2b + (size_t)(t + 1)*W + cbase;
            xa1 = r1[xsl1];  xa2 = r2[xsl1];
            xb1 = r1[xsl2];  xb2 = r2[xsl2];
            if (xe3) { xc1 = r1[xsl3]; xc2 = r2[xsl3]; }
        }

        uint4 bu[5][3];
        uint32_t stash[5][3];
        float pv[5];

        auto tilecomp = [&](int ti) {
            union { uint4 u; f16x8 v; } c0, c1, c2;
            c0.u = bu[ti][0]; c1.u = bu[ti][1]; c2.u = bu[ti][2];
            f32x16 acc = __builtin_amdgcn_mfma_f32_32x32x16_f16(afrag[0], c0.v, bias16, 0, 0, 0);
            acc = __builtin_amdgcn_mfma_f32_32x32x16_f16(afrag[1], c1.v, acc, 0, 0, 0);
            acc = __builtin_amdgcn_mfma_f32_32x32x16_f16(afrag[2], c2.v, acc, 0, 0, 0);
            h2 p0 = __builtin_elementwise_max(__builtin_amdgcn_cvt_pkrtz(acc[0], acc[1]), hz);
            h2 p1 = __builtin_elementwise_max(__builtin_amdgcn_cvt_pkrtz(acc[2], acc[3]), hz);
            h2 p2 = __builtin_elementwise_max(__builtin_amdgcn_cvt_pkrtz(acc[4], acc[5]), hz);
            stash[ti][0] = as_u32(p0); stash[ti][1] = as_u32(p1); stash[ti][2] = as_u32(p2);
            float pc = __builtin_amdgcn_fdot2(wop2, p2,
                       __builtin_amdgcn_fdot2(wop1, p1,
                       __builtin_amdgcn_fdot2(wop0, p0, 0.f, false), false), false);
            int pi = __builtin_amdgcn_ds_bpermute(bpaddr, __builtin_bit_cast(int, pc));
            pv[ti] = pc + __builtin_bit_cast(float, pi);
        };
        auto tilewrite = [&](int ti) {
            bool skip_halo = sync && isEW && (ti == hti);
            if (wok[ti] && !skip_halo) {
                uint32_t* rp = wb + aw_[ti];
                uint2 wr; wr.x = stash[ti][0]; wr.y = stash[ti][1];
                *(uint2*)rp = wr;
                if (hh == 0) wb[bw_[ti]] = stash[ti][2];
            }
        };

        // ---- pass 1: INTERIOR tiles (own-wave data only; no gate) ----
        #pragma unroll
        for (int ti = 0; ti < 5; ++ti)
            if (ti < nti && !gated_[ti])
                #pragma unroll
                for (int tap = 0; tap < 3; ++tap)
                    bu[ti][tap] = *(const uint4*)(rb + rdi_[ti] + 4*tap);
        #pragma unroll
        for (int ti = 0; ti < 5; ++ti)
            if (ti < nti && !gated_[ti]) tilecomp(ti);
        #pragma unroll
        for (int ti = 0; ti < 5; ++ti)
            if (ti < nti && !gated_[ti]) tilewrite(ti);

        // halo exchange PUBLISH early (payload tile sti is interior for both EW kinds)
        if (sync && isEW) {
            uint32_t* rec = rec_m + (((t >> 5) & 1) ? 256 : 0);
            if (hh == 0) {
                __hip_atomic_store(rec + 32 +   0 + m, stash[sti][0], __ATOMIC_RELAXED, __HIP_MEMORY_SCOPE_AGENT);
                __hip_atomic_store(rec + 32 +  32 + m, stash[sti][1], __ATOMIC_RELAXED, __HIP_MEMORY_SCOPE_AGENT);
                __hip_atomic_store(rec + 32 + 128 + m, stash[sti][2], __ATOMIC_RELAXED, __HIP_MEMORY_SCOPE_AGENT);
            } else {
                __hip_atomic_store(rec + 32 +  64 + m, stash[sti][0], __ATOMIC_RELAXED, __HIP_MEMORY_SCOPE_AGENT);
                __hip_atomic_store(rec + 32 +  96 + m, stash[sti][1], __ATOMIC_RELAXED, __HIP_MEMORY_SCOPE_AGENT);
            }
            if (lane == 0)   // release waits the wave's outstanding stores
                __hip_atomic_store(rec, (uint32_t)t, __ATOMIC_RELEASE, __HIP_MEMORY_SCOPE_AGENT);
        }

        // ---- intra-block neighbor gate (now AFTER the bulk of the work) ----
        if (t >= 2) {
            const uint32_t need = (uint32_t)(t - 1);
            while (__hip_atomic_load(&fl[na], __ATOMIC_ACQUIRE, __HIP_MEMORY_SCOPE_WORKGROUP) < need ||
                   __hip_atomic_load(&fl[nb], __ATOMIC_ACQUIRE, __HIP_MEMORY_SCOPE_WORKGROUP) < need)
                __builtin_amdgcn_s_sleep(1);
        }

        // ---- pass 2: GATED tiles (touch neighbor columns) ----
        #pragma unroll
        for (int ti = 0; ti < 5; ++ti)
            if (ti < nti && gated_[ti])
                #pragma unroll
                for (int tap = 0; tap < 3; ++tap)
                    bu[ti][tap] = *(const uint4*)(rb + rdi_[ti] + 4*tap);
        #pragma unroll
        for (int ti = 0; ti < 5; ++ti)
            if (ti < nti && gated_[ti]) tilecomp(ti);
        #pragma unroll
        for (int ti = 0; ti < 5; ++ti)
            if (ti < nti && gated_[ti]) tilewrite(ti);

        // x writes (boundary x slots are neighbor-read -> must stay post-gate)
        if (pf) {
            wb[BBASE + 4*xsl1 + 1] = as_u32(__builtin_amdgcn_cvt_pkrtz(xa1, xa2));
            wb[BBASE + 4*xsl2 + 1] = as_u32(__builtin_amdgcn_cvt_pkrtz(xb1, xb2));
            if (xe3) wb[BBASE + 4*xsl3 + 1] = as_u32(__builtin_amdgcn_cvt_pkrtz(xc1, xc2));
        }

        // intra publish (release fences this wave's LDS writes)
        if (lane == 0)
            __hip_atomic_store(&fl[wvL], (uint32_t)t, __ATOMIC_RELEASE, __HIP_MEMORY_SCOPE_WORKGROUP);

        // out-store (global; issues under the consume spin below)
        #pragma unroll
        for (int i = 0; i < 2; ++i) {
            const int oti = obase + 2*hh + i;
            const int c = col_[oti];
            float val = (c == 0 || c == W-1) ? bov : pv[oti] + bov;
            outb[(size_t)t*W + c] = val;
        }

        // halo exchange CONSUME (edge wave): refresh halo slots of row-t buffer.
        if (sync && isEW) {
            uint32_t* rec = rec_o + (((t >> 5) & 1) ? 256 : 0);
            while (__hip_atomic_load(rec, __ATOMIC_ACQUIRE, __HIP_MEMORY_SCOPE_AGENT) < (uint32_t)t)
                __builtin_amdgcn_s_sleep(2);
            const int rslot = (hfl ? 1 : 1025) + m;        // received col -> slot
            if (hh == 0) {
                uint32_t d0 = __hip_atomic_load(rec + 32 +   0 + m, __ATOMIC_RELAXED, __HIP_MEMORY_SCOPE_AGENT);
                uint32_t d1 = __hip_atomic_load(rec + 32 +  32 + m, __ATOMIC_RELAXED, __HIP_MEMORY_SCOPE_AGENT);
                uint32_t d2 = __hip_atomic_load(rec + 32 + 128 + m, __ATOMIC_RELAXED, __HIP_MEMORY_SCOPE_AGENT);
                uint2 wr; wr.x = d0; wr.y = d1;
                *(uint2*)(wb + ABASE + 4*rslot) = wr;      // c01,c23
                wb[BBASE + 4*rslot] = d2;                  // c89
            } else {
                uint32_t d0 = __hip_atomic_load(rec + 32 +  64 + m, __ATOMIC_RELAXED, __HIP_MEMORY_SCOPE_AGENT);
                uint32_t d1 = __hip_atomic_load(rec + 32 +  96 + m, __ATOMIC_RELAXED, __HIP_MEMORY_SCOPE_AGENT);
                uint2 wr; wr.x = d0; wr.y = d1;
                *(uint2*)(wb + ABASE + 4*rslot + 2) = wr;  // c45,c67
            }
        }
    }
}

extern "C" void kernel_launch(void* const* d_in, const int* in_sizes, int n_in,
                              void* d_out, int out_size, void* d_ws, size_t ws_size,
                              hipStream_t stream)
{
    const float* x  = (const float*)d_in[0];
    const float* w1 = (const float*)d_in[1];
    const float* b1 = (const float*)d_in[2];
    const float* w2 = (const float*)d_in[3];
    const float* b2 = (const float*)d_in[4];
    const float* wl = (const float*)d_in[5];
    const float* bl = (const float*)d_in[6];
    const float* wo = (const float*)d_in[7];
    const float* bo = (const float*)d_in[8];
    float* out = (float*)d_out;

    hipMemsetAsync(d_ws, 0, 8*2*512*sizeof(uint32_t), stream);   // reset exchange tags

    const int shbytes = (2*BUFD + NW) * sizeof(uint32_t);   // ~82 KB -> 1 block/CU
    hipFuncSetAttribute((const void*)recurrent_kernel,
                        hipFuncAttributeMaxDynamicSharedMemorySize, shbytes);
    recurrent_kernel<<<16, 512, shbytes, stream>>>(x, w1, b1, w2, b2, wl, bl, wo, bo,
                                                   out, (uint32_t*)d_ws);
}

// Round 11
// 771.642 us; speedup vs baseline: 1.3566x; 1.3566x over previous
//
#include <hip/hip_runtime.h>
#include <cstdint>

#define W 2048
#define H 512
#define K 32                     // halo depth = sync period (steps)
#define NW 16                    // waves per block
#define NSLOT 1058               // slots 0..1057 ; slot s <-> col s + cbase
// Split-array LDS layout per buffer (16B/slot both -> uniform full-exec b128 reads):
//   arrA: NSLOT x 4 dw: {c01,c23,c45,c67}   arrB: NSLOT x 4 dw: {c89, x-pair, 0, 0}
#define ABASE 0
#define BBASE (NSLOT*4)
#define BUFD  10248              // raw 8464, padded: 2 buffers = 82 KB -> 1 block/CU
#define FLOFF (2*BUFD)

typedef __fp16 h2    __attribute__((ext_vector_type(2)));
typedef __fp16 f16x8 __attribute__((ext_vector_type(8)));
typedef float  f32x16 __attribute__((ext_vector_type(16)));

static __device__ __forceinline__ h2 as_h2(uint32_t u){ union{uint32_t u; h2 h;} x; x.u=u; return x.h; }
static __device__ __forceinline__ uint32_t as_u32(h2 h){ union{uint32_t u; h2 h;} x; x.h=h; return x.u; }

__global__ __launch_bounds__(1024, 1) void recurrent_kernel(
    const float* __restrict__ x,
    const float* __restrict__ w1, const float* __restrict__ b1,
    const float* __restrict__ w2, const float* __restrict__ b2,
    const float* __restrict__ wl, const float* __restrict__ bl,
    const float* __restrict__ wo, const float* __restrict__ bo,
    float* __restrict__ out, uint32_t* __restrict__ ws)
{
    extern __shared__ uint32_t lds[];
    const int tid  = threadIdx.x;
    const int b    = blockIdx.x & 7;     // batch
    const int hfl  = blockIdx.x >> 3;    // half: 0 = owns cols 0..1023, 1 = owns 1024..2047
    const int lane = tid & 63;
    const int wvL  = tid >> 6;           // wave 0..15
    const int m    = lane & 31;
    const int hh   = lane >> 5;

    const int cbase = hfl ? 991 : -1;    // col = slot + cbase
    // edge wave (owns halo tile): hfl0 -> wave 15 (right), hfl1 -> wave 0 (left)
    const bool isEW = (hfl == 0) ? (wvL == NW-1) : (wvL == 0);
    const int nti   = isEW ? 3 : 2;      // tiles this wave computes (ti2 = halo)
    const int sti   = hfl ? 0 : 1;       // local index of boundary tile we SEND

    for (int i = tid; i < 2*BUFD + NW; i += 1024) lds[i] = 0;

    // ---- A fragments: weights resident in VGPRs ----
    f16x8 afrag[3];
    #pragma unroll
    for (int tap = 0; tap < 3; ++tap)
        #pragma unroll
        for (int j = 0; j < 8; ++j) {
            int k = 8*hh + j;
            float v = (m < 10 && k < 12) ? wl[(m*12 + k)*3 + tap] : 0.f;
            afrag[tap][j] = (__fp16)v;
        }
    h2 wop0, wop1, wop2;
    if (hh == 0) {
        wop0 = __builtin_amdgcn_cvt_pkrtz(wo[0], wo[1]);
        wop1 = __builtin_amdgcn_cvt_pkrtz(wo[2], wo[3]);
        wop2 = __builtin_amdgcn_cvt_pkrtz(wo[8], wo[9]);
    } else {
        wop0 = __builtin_amdgcn_cvt_pkrtz(wo[4], wo[5]);
        wop1 = __builtin_amdgcn_cvt_pkrtz(wo[6], wo[7]);
        wop2 = __builtin_amdgcn_cvt_pkrtz(0.f, 0.f);
    }
    f32x16 bias16;
    #pragma unroll
    for (int r = 0; r < 16; ++r) {
        int ch = (r & 3) + 8*(r >> 2) + 4*hh;
        bias16[r] = (r < 8 && ch < 10) ? bl[ch] : 0.f;
    }
    const float bov = bo[0];
    const int bpaddr = (lane ^ 32) << 2;
    const h2 hz = {(__fp16)0.f, (__fp16)0.f};

    const float* x1b = x + (((size_t)b*3 + 1)*H)*W;
    const float* x2b = x + (((size_t)b*3 + 2)*H)*W;
    float* outb = out + (size_t)b*H*W;

    // ---- per-wave tile geometry (global tile gt covers write-slots 32gt+1..32gt+32) ----
    // hfl0: wave w -> gt {2w, 2w+1}; wave 15 also halo gt 32 (slots 1025..1056)
    // hfl1: wave 0 -> gt {1, 2} + halo gt 0 (slots 1..32); wave w>=1 -> gt {2w+1, 2w+2}
    int rdi_[3], aw_[3], bw_[3], col_[3];
    bool wok[3];
    #pragma unroll
    for (int ti = 0; ti < 3; ++ti) {
        int gt = (hfl == 0) ? (ti < 2 ? 2*wvL + ti : 32)
                            : (wvL == 0 ? (ti < 2 ? ti + 1 : 0) : 2*wvL + 1 + ti);
        int sb = 32*gt + m;                    // read slot base (tap 0)
        rdi_[ti] = (hh ? BBASE : ABASE) + 4*sb;
        aw_[ti]  = ABASE + 4*(sb + 1) + 2*hh;
        bw_[ti]  = BBASE + 4*(sb + 1);
        col_[ti] = 32*gt + m + (hfl ? 992 : 0);
        wok[ti]  = (col_[ti] != 0) && (col_[ti] != W-1);
    }
    uint32_t* fl = lds + FLOFF;
    const int na = (wvL == 0)    ? wvL : wvL - 1;
    const int nb = (wvL == NW-1) ? wvL : wvL + 1;

    // exchange records: [b][dir] : 512 dw each; parity slot 256 dw: tag@0, data@32+32*f+m
    uint32_t* rec_m = ws + (b*2 + hfl)*512;
    uint32_t* rec_o = ws + (b*2 + (1 - hfl))*512;

    // x-prefetch ownership == row-write ownership (contiguous; distance-<=1 coupling)
    // hfl0 w<15: slots 64w+1..64w+64 ; w15: 961..1056
    // hfl1 w0: slots 1..96 ; w>=1: 64w+33..64w+96
    const int xbase = (hfl == 0) ? (64*wvL + 1) : (wvL == 0 ? 1 : 64*wvL + 33);
    const int xsl1 = xbase + lane;
    const bool xe2 = isEW && (hh == 0);
    const int xsl2 = xbase + 64 + m;

    __syncthreads();   // zeros visible

    // ---- init: row0 for ALL slots (ghosts/guards included) + out[0] for owned ----
    for (int idx = tid; idx < NSLOT; idx += 1024) {
        const int p = idx + cbase;                 // global col of slot idx
        float fi[3][5];
        #pragma unroll
        for (int l = 0; l < 5; ++l) {
            int v = p - 2 + l;
            bool ok = (v >= 0) && (v < W);
            fi[0][l] = ok ? x[(((size_t)b*3 + 0)*H + (H-1))*W + v] : 0.f;
            fi[1][l] = ok ? x1b[v] : 0.f;
            fi[2][l] = ok ? x2b[v] : 0.f;
        }
        float h1v[5][3];
        #pragma unroll
        for (int c = 0; c < 5; ++c)
            #pragma unroll
            for (int i3 = 0; i3 < 3; ++i3) {
                int u = p - 2 + i3;
                float a = b1[c];
                #pragma unroll
                for (int j = 0; j < 3; ++j)
                    #pragma unroll
                    for (int k = 0; k < 3; ++k)
                        a += w1[(c*3 + j)*3 + k] * fi[j][i3 + k];
                h1v[c][i3] = (u >= 0 && u <= W-3) ? fmaxf(a, 0.f) : 0.f;
            }
        const bool valid = (p >= 1) && (p <= W-2);
        float h2c[10];
        #pragma unroll
        for (int c2 = 0; c2 < 10; ++c2) {
            float a = b2[c2];
            #pragma unroll
            for (int c = 0; c < 5; ++c)
                #pragma unroll
                for (int k = 0; k < 3; ++k)
                    a += w2[(c2*5 + c)*3 + k] * h1v[c][k];
            h2c[c2] = valid ? fmaxf(a, 0.f) : 0.f;
        }
        uint4 wr;
        wr.x = as_u32(__builtin_amdgcn_cvt_pkrtz(h2c[0], h2c[1]));
        wr.y = as_u32(__builtin_amdgcn_cvt_pkrtz(h2c[2], h2c[3]));
        wr.z = as_u32(__builtin_amdgcn_cvt_pkrtz(h2c[4], h2c[5]));
        wr.w = as_u32(__builtin_amdgcn_cvt_pkrtz(h2c[6], h2c[7]));
        *(uint4*)(lds + ABASE + 4*idx) = wr;
        lds[BBASE + 4*idx] = as_u32(__builtin_amdgcn_cvt_pkrtz(h2c[8], h2c[9]));
        bool okp = (p >= 0) && (p < W);
        lds[BBASE + 4*idx + 1] = okp
            ? as_u32(__builtin_amdgcn_cvt_pkrtz(x1b[W + p], x2b[W + p])) : 0u;
        if (p >= hfl*1024 && p < hfl*1024 + 1024) {   // owned col -> out[0]
            float s = bov;
            #pragma unroll
            for (int c = 0; c < 10; ++c) s += wo[c]*h2c[c];
            outb[p] = s;
        }
    }
    __syncthreads();   // last block-wide barrier

    // ---- recurrence: neighbor-gated wave pipeline + K-deep halo exchange ----
    #pragma unroll 1
    for (int t = 1; t < H; ++t) {
        const uint32_t* rb = lds + ((t - 1) & 1)*BUFD;   // row t-1 + x[t]
        uint32_t*       wb = lds + (t & 1)*BUFD;         // row t   + x[t+1]
        const bool sync = ((t & (K-1)) == 0);            // t = 32,64,...,480

        // x[t+1] prefetch (wave-owned slots)
        float xa1, xa2, xc1 = 0.f, xc2 = 0.f;
        const bool pf = (t + 1 < H);
        if (pf) {
            const float* r1 = x1b + (size_t)(t + 1)*W + cbase;
            const float* r2 = x2b + (size_t)(t + 1)*W + cbase;
            xa1 = r1[xsl1];  xa2 = r2[xsl1];
            if (xe2) { xc1 = r1[xsl2]; xc2 = r2[xsl2]; }
        }

        // intra-block neighbor gate (R5-proven form: s_sleep backoff)
        if (t >= 2) {
            const uint32_t need = (uint32_t)(t - 1);
            while (__hip_atomic_load(&fl[na], __ATOMIC_ACQUIRE, __HIP_MEMORY_SCOPE_WORKGROUP) < need ||
                   __hip_atomic_load(&fl[nb], __ATOMIC_ACQUIRE, __HIP_MEMORY_SCOPE_WORKGROUP) < need)
                __builtin_amdgcn_s_sleep(1);
        }

        // phase A: uniform full-exec b128 reads (3rd tile on edge wave only)
        uint4 bu[3][3];
        #pragma unroll
        for (int ti = 0; ti < 3; ++ti)
            if (ti < nti)
                #pragma unroll
                for (int tap = 0; tap < 3; ++tap)
                    bu[ti][tap] = *(const uint4*)(rb + rdi_[ti] + 4*tap);

        uint32_t stash[3][3];
        float pv[3];
        #pragma unroll
        for (int ti = 0; ti < 3; ++ti) {
            if (ti >= nti) continue;
            union { uint4 u; f16x8 v; } c0, c1, c2;
            c0.u = bu[ti][0]; c1.u = bu[ti][1]; c2.u = bu[ti][2];
            f32x16 acc = __builtin_amdgcn_mfma_f32_32x32x16_f16(afrag[0], c0.v, bias16, 0, 0, 0);
            acc = __builtin_amdgcn_mfma_f32_32x32x16_f16(afrag[1], c1.v, acc, 0, 0, 0);
            acc = __builtin_amdgcn_mfma_f32_32x32x16_f16(afrag[2], c2.v, acc, 0, 0, 0);
            h2 p0 = __builtin_elementwise_max(__builtin_amdgcn_cvt_pkrtz(acc[0], acc[1]), hz);
            h2 p1 = __builtin_elementwise_max(__builtin_amdgcn_cvt_pkrtz(acc[2], acc[3]), hz);
            h2 p2 = __builtin_elementwise_max(__builtin_amdgcn_cvt_pkrtz(acc[4], acc[5]), hz);
            stash[ti][0] = as_u32(p0); stash[ti][1] = as_u32(p1); stash[ti][2] = as_u32(p2);
            // fused 1x1 conv: this half's channels + other half via bpermute (proven form)
            float pc = __builtin_amdgcn_fdot2(wop2, p2,
                       __builtin_amdgcn_fdot2(wop1, p1,
                       __builtin_amdgcn_fdot2(wop0, p0, 0.f, false), false), false);
            int pi = __builtin_amdgcn_ds_bpermute(bpaddr, __builtin_bit_cast(int, pc));
            pv[ti] = pc + __builtin_bit_cast(float, pi);
        }

        // halo exchange PUBLISH (edge wave, sync steps): boundary tile is exact here.
        if (sync && isEW) {
            uint32_t* rec = rec_m + (((t >> 5) & 1) ? 256 : 0);
            if (hh == 0) {
                __hip_atomic_store(rec + 32 +   0 + m, stash[sti][0], __ATOMIC_RELAXED, __HIP_MEMORY_SCOPE_AGENT);
                __hip_atomic_store(rec + 32 +  32 + m, stash[sti][1], __ATOMIC_RELAXED, __HIP_MEMORY_SCOPE_AGENT);
                __hip_atomic_store(rec + 32 + 128 + m, stash[sti][2], __ATOMIC_RELAXED, __HIP_MEMORY_SCOPE_AGENT);
            } else {
                __hip_atomic_store(rec + 32 +  64 + m, stash[sti][0], __ATOMIC_RELAXED, __HIP_MEMORY_SCOPE_AGENT);
                __hip_atomic_store(rec + 32 +  96 + m, stash[sti][1], __ATOMIC_RELAXED, __HIP_MEMORY_SCOPE_AGENT);
            }
            if (lane == 0)   // release waits the wave's outstanding stores
                __hip_atomic_store(rec, (uint32_t)t, __ATOMIC_RELEASE, __HIP_MEMORY_SCOPE_AGENT);
        }

        // phase B: write row t (skip decayed halo tile at sync; exchange will fill it)
        #pragma unroll
        for (int ti = 0; ti < 3; ++ti) {
            if (ti >= nti) continue;
            bool skip_halo = sync && isEW && (ti == 2);
            if (wok[ti] && !skip_halo) {
                uint32_t* rp = wb + aw_[ti];
                uint2 wr; wr.x = stash[ti][0]; wr.y = stash[ti][1];
                *(uint2*)rp = wr;
                if (hh == 0) wb[bw_[ti]] = stash[ti][2];
            }
        }
        if (pf) {
            wb[BBASE + 4*xsl1 + 1] = as_u32(__builtin_amdgcn_cvt_pkrtz(xa1, xa2));
            if (xe2) wb[BBASE + 4*xsl2 + 1] = as_u32(__builtin_amdgcn_cvt_pkrtz(xc1, xc2));
        }

        // intra publish (release fences this wave's LDS writes)
        if (lane == 0)
            __hip_atomic_store(&fl[wvL], (uint32_t)t, __ATOMIC_RELEASE, __HIP_MEMORY_SCOPE_WORKGROUP);

        // out-store: owned tiles are always ti 0,1 -> one col per lane (pv same in both halves)
        {
            const int oti = hh;
            const int c = col_[oti];
            float val = (c == 0 || c == W-1) ? bov : pv[oti] + bov;
            outb[(size_t)t*W + c] = val;
        }

        // halo exchange CONSUME (edge wave): refresh halo slots of row-t buffer.
        if (sync && isEW) {
            uint32_t* rec = rec_o + (((t >> 5) & 1) ? 256 : 0);
            while (__hip_atomic_load(rec, __ATOMIC_ACQUIRE, __HIP_MEMORY_SCOPE_AGENT) < (uint32_t)t)
                __builtin_amdgcn_s_sleep(2);
            const int rslot = (hfl ? 1 : 1025) + m;        // received col -> slot
            if (hh == 0) {
                uint32_t d0 = __hip_atomic_load(rec + 32 +   0 + m, __ATOMIC_RELAXED, __HIP_MEMORY_SCOPE_AGENT);
                uint32_t d1 = __hip_atomic_load(rec + 32 +  32 + m, __ATOMIC_RELAXED, __HIP_MEMORY_SCOPE_AGENT);
                uint32_t d2 = __hip_atomic_load(rec + 32 + 128 + m, __ATOMIC_RELAXED, __HIP_MEMORY_SCOPE_AGENT);
                uint2 wr; wr.x = d0; wr.y = d1;
                *(uint2*)(wb + ABASE + 4*rslot) = wr;      // c01,c23
                wb[BBASE + 4*rslot] = d2;                  // c89
            } else {
                uint32_t d0 = __hip_atomic_load(rec + 32 +  64 + m, __ATOMIC_RELAXED, __HIP_MEMORY_SCOPE_AGENT);
                uint32_t d1 = __hip_atomic_load(rec + 32 +  96 + m, __ATOMIC_RELAXED, __HIP_MEMORY_SCOPE_AGENT);
                uint2 wr; wr.x = d0; wr.y = d1;
                *(uint2*)(wb + ABASE + 4*rslot + 2) = wr;  // c45,c67
            }
        }
    }
}

extern "C" void kernel_launch(void* const* d_in, const int* in_sizes, int n_in,
                              void* d_out, int out_size, void* d_ws, size_t ws_size,
                              hipStream_t stream)
{
    const float* x  = (const float*)d_in[0];
    const float* w1 = (const float*)d_in[1];
    const float* b1 = (const float*)d_in[2];
    const float* w2 = (const float*)d_in[3];
    const float* b2 = (const float*)d_in[4];
    const float* wl = (const float*)d_in[5];
    const float* bl = (const float*)d_in[6];
    const float* wo = (const float*)d_in[7];
    const float* bo = (const float*)d_in[8];
    float* out = (float*)d_out;

    hipMemsetAsync(d_ws, 0, 8*2*512*sizeof(uint32_t), stream);   // reset exchange tags

    const int shbytes = (2*BUFD + NW) * sizeof(uint32_t);   // ~82 KB -> 1 block/CU
    hipFuncSetAttribute((const void*)recurrent_kernel,
                        hipFuncAttributeMaxDynamicSharedMemorySize, shbytes);
    recurrent_kernel<<<16, 1024, shbytes, stream>>>(x, w1, b1, w2, b2, wl, bl, wo, bo,
                                                    out, (uint32_t*)d_ws);
}